// Round 5
// baseline (86.943 us; speedup 1.0000x reference)
//
#include <hip/hip_runtime.h>

// LogicConv3d: B=4, C=3, H=W=D=32, K=32, S=16 leaves, tree depth 4 (31 LUT nodes).
// Out: (B, K, 30, 30, 30) = 3,456,000 fp32.
//
// R15: convoy-breaking. Evidence: pipe swaps (R5/R9/R10), +33% occupancy (R11),
// -50% staging (R12), manual pipelining (R14) ALL neutral; issue model says
// 5.8us vs ~25us measured -> SIMDs issue ~25% of the time. Remaining invariant:
// all 16 waves/CU leave the same barrier and run identical streams -> every
// gather cluster is a population-wide burst -> queueing inflates latency and
// all waves stall TOGETHER (cross-wave hiding impossible). Fixes:
//  1) all-LDS gathers (B-tree from slab too): 120cyc latency, no L1 queue,
//     LDS pipe has 2x headroom (~3.4us/CU of data time at 16 waves)
//  2) depth-first tree: live state 64->~48 VGPR -> scheduler hoists ~2x more
//     gathers in flight under the 128-VGPR cap
//  3) wave-parity kk-stagger: odd waves run kk=1 first (wave-uniform branch,
//     compile-time indexing in both bodies) -> half the waves' load clusters
//     overlap the other half's FMA clusters.
// Structure otherwise = R13: 512 thr, 4 oh-rows, slab 3c x 6h x 32 x 33 dw
// (76,032B, 2 blocks/CU), k-pair per block, bases via readfirstlane -> SGPRs.

#define B_  4
#define C_  3
#define H_  32
#define W_  32
#define D_  32
#define K_  32
#define S_  16
#define WS  33      // padded d-row stride (dwords); %32==1 rotates banks per ow
#define TPB 512

typedef float v8f __attribute__((ext_vector_type(8), aligned(4)));

__device__ __forceinline__ v8f lut8(v8f a, v8f b, float l0, float d1, float d2, float d3) {
    // E = l0 + a*d2 + b*d1 + (a*b)*d3 == fma(b, fma(a,d3,d1), fma(a,d2,l0))
    const v8f t0 = a * d2 + l0;
    const v8f t1 = a * d3 + d1;
    return b * t1 + t0;
}

__global__ __launch_bounds__(TPB, 4) void logic_conv3d(
    const float* __restrict__ x,
    const int*   __restrict__ kc,
    const float* __restrict__ w0,
    const float* __restrict__ w1,
    const float* __restrict__ w2,
    const float* __restrict__ w3,
    const float* __restrict__ w4,
    float*       __restrict__ out)
{
    __shared__ float4 s_lut[2][31];              // (l0, d1, d2, d3) per node, per kk
    __shared__ __align__(16) int s_lb[2][16];    // tree-0 leaf base, slab coords, per kk
    __shared__ __align__(16) int s_gb[2][16];    // tree-1 leaf base, slab coords, per kk
    __shared__ __align__(16) float slab[18 * 32 * WS];  // 19008 dwords = 76032 B

    const int bx  = blockIdx.x;      // b*16 + kp
    const int b   = bx >> 4;
    const int k0  = (bx & 15) << 1;  // first k of this block's pair
    const int tid = threadIdx.x;
    const int oh0 = blockIdx.y * 4;  // first oh row of this block (0,4,...,28)

    // ---- per-block setup: 2 x (31 softmax->LUT delta form) + 2 x 32 leaf bases ----
    if (tid < 62) {
        const int kk   = (tid >= 31) ? 1 : 0;
        const int node = tid - kk * 31;
        const int k    = k0 + kk;
        const float* wp; int ln;
        if      (node < 16) { wp = w0; ln = node;      }
        else if (node < 24) { wp = w1; ln = node - 16; }
        else if (node < 28) { wp = w2; ln = node - 24; }
        else if (node < 30) { wp = w3; ln = node - 28; }
        else                { wp = w4; ln = 0;         }
        const float* wrow = wp + (ln * K_ + k) * 16;
        float lg[16];
        float m = -1e30f;
        #pragma unroll
        for (int g = 0; g < 16; ++g) { lg[g] = wrow[g]; m = fmaxf(m, lg[g]); }
        float z = 0.f;
        #pragma unroll
        for (int g = 0; g < 16; ++g) { lg[g] = __expf(lg[g] - m); z += lg[g]; }
        const float inv = 1.0f / z;
        float l0 = 0.f, l1 = 0.f, l2 = 0.f, l3 = 0.f;
        #pragma unroll
        for (int g = 0; g < 16; ++g) {
            float p = lg[g] * inv;           // GATES[g,t] = (g>>t)&1, t = 2*a+b
            if (g & 1) l0 += p;
            if (g & 2) l1 += p;
            if (g & 4) l2 += p;
            if (g & 8) l3 += p;
        }
        s_lut[kk][node] = make_float4(l0, l1 - l0, l2 - l0, (l3 - l2) - (l1 - l0));
    } else if (tid >= 64 && tid < 128) {
        const int idx  = tid - 64;           // kk*32 + tree*16 + s
        const int kk   = idx >> 5;
        const int tree = (idx >> 4) & 1;
        const int s    = idx & 15;
        const int k    = k0 + kk;
        const int off  = ((tree * K_ + k) * S_ + s) * 4;  // kc (2,K,S,4) = (h,w,d,c)
        const int h = kc[off + 0], w = kc[off + 1], d = kc[off + 2], c = kc[off + 3];
        const int sb = ((c * 6 + h) * 32 + w) * WS + d;   // slab coords (6 h-rows)
        if (tree == 0) s_lb[kk][s] = sb;
        else           s_gb[kk][s] = sb;
    }

    // ---- stage slab: 18 planes (3c x 6h) of 32x32 dwords, coalesced float4 ----
    {
        const float* xb = x + (size_t)b * (C_ * H_ * W_ * D_);
        #pragma unroll
        for (int it = 0; it < 9; ++it) {
            const int idx   = it * TPB + tid;   // float4 index, 0..4607 (18*256)
            const int plane = idx >> 8;         // 0..17 = c*6 + dh
            const int f4    = idx & 255;
            const int c     = plane / 6;
            const int dh    = plane - c * 6;
            const int h     = min(oh0 + dh, H_ - 1);   // clamp for y=7 tail (values unused)
            const int w     = f4 >> 3;          // 0..31
            const int d4    = (f4 & 7) << 2;    // 0,4,...,28
            const float4 val = *(const float4*)(xb + ((c * H_ + h) * W_ + w) * D_ + d4);
            *(float4*)&slab[(plane * 32 + w) * WS + d4] = val;
        }
    }
    __syncthreads();

    // ---- bases for BOTH kk: aligned b128 reads + readfirstlane -> SGPRs ----
    int sA[2][16], sB[2][16];
    #pragma unroll
    for (int kk = 0; kk < 2; ++kk) {
        #pragma unroll
        for (int i = 0; i < 4; ++i) {
            const int4 qa = *(const int4*)&s_lb[kk][i * 4];
            sA[kk][i * 4 + 0] = __builtin_amdgcn_readfirstlane(qa.x);
            sA[kk][i * 4 + 1] = __builtin_amdgcn_readfirstlane(qa.y);
            sA[kk][i * 4 + 2] = __builtin_amdgcn_readfirstlane(qa.z);
            sA[kk][i * 4 + 3] = __builtin_amdgcn_readfirstlane(qa.w);
            const int4 qb = *(const int4*)&s_gb[kk][i * 4];
            sB[kk][i * 4 + 0] = __builtin_amdgcn_readfirstlane(qb.x);
            sB[kk][i * 4 + 1] = __builtin_amdgcn_readfirstlane(qb.y);
            sB[kk][i * 4 + 2] = __builtin_amdgcn_readfirstlane(qb.z);
            sB[kk][i * 4 + 3] = __builtin_amdgcn_readfirstlane(qb.w);
        }
    }

    // thread -> (oh_local 0..3, ow, octet of consecutive od)
    const int ohl = tid >> 7;                // 0..3
    const int r   = tid & 127;
    const int ow  = r >> 2;                  // 0..31 (>=30 inactive)
    const int gq  = r & 3;                   // 0..3
    const int od0 = (gq < 3) ? (gq << 3) : 22;  // 0,8,16,22; gq=3 overlaps gq=2 by 2
    const int oh  = oh0 + ohl;

    if (ow < 30 && oh < 30) {
        const int vo = ohl * (32 * WS) + ow * WS + od0;             // slab offset

        #define LD_T0(kk, s) (*(const v8f*)&slab[sA[kk][s] + vo])
        #define LD_T1(kk, s) (*(const v8f*)&slab[sB[kk][s] + vo])

        // depth-first tree for one k: live state <= v2[4] + pair temps (~48 VGPR)
        #define KK_BODY(kk) do {                                                  \
            v8f v2[4];                                                            \
            _Pragma("unroll")                                                     \
            for (int q = 0; q < 4; ++q) {                                         \
                v8f tl[2];                                                        \
                _Pragma("unroll")                                                 \
                for (int u = 0; u < 2; ++u) {                                     \
                    const int j = 2 * q + u;                                      \
                    const v8f A0 = LD_T0(kk, 2 * j);                              \
                    const v8f B0 = LD_T1(kk, 2 * j);                              \
                    const float4 L0 = s_lut[kk][2 * j];                           \
                    const v8f t0 = lut8(A0, B0, L0.x, L0.y, L0.z, L0.w);          \
                    const v8f A1 = LD_T0(kk, 2 * j + 1);                          \
                    const v8f B1 = LD_T1(kk, 2 * j + 1);                          \
                    const float4 L1 = s_lut[kk][2 * j + 1];                       \
                    const v8f t1 = lut8(A1, B1, L1.x, L1.y, L1.z, L1.w);          \
                    const float4 LN = s_lut[kk][16 + j];                          \
                    tl[u] = lut8(t0, t1, LN.x, LN.y, LN.z, LN.w);                 \
                }                                                                 \
                const float4 L2 = s_lut[kk][24 + q];                              \
                v2[q] = lut8(tl[0], tl[1], L2.x, L2.y, L2.z, L2.w);               \
            }                                                                     \
            const float4 La = s_lut[kk][28];                                      \
            const v8f u0 = lut8(v2[0], v2[1], La.x, La.y, La.z, La.w);            \
            const float4 Lb = s_lut[kk][29];                                      \
            const v8f u1 = lut8(v2[2], v2[3], Lb.x, Lb.y, Lb.z, Lb.w);            \
            const float4 Lc = s_lut[kk][30];                                      \
            const v8f u2 = lut8(u0, u1, Lc.x, Lc.y, Lc.z, Lc.w);                  \
            const int bk = b * K_ + k0 + (kk);                                    \
            float* outp = out + (size_t)bk * 27000 + oh * 900 + ow * 30 + od0;    \
            *(v8f*)outp = u2;                                                     \
        } while (0)

        // wave-parity kk-stagger: desynchronize load clusters across the wave
        // population (wave-uniform branch; both bodies fully compile-time-indexed)
        const int wpar = (tid >> 6) & 1;
        if (wpar == 0) { KK_BODY(0); KK_BODY(1); }
        else           { KK_BODY(1); KK_BODY(0); }

        #undef KK_BODY
        #undef LD_T0
        #undef LD_T1
    }
}

extern "C" void kernel_launch(void* const* d_in, const int* in_sizes, int n_in,
                              void* d_out, int out_size, void* d_ws, size_t ws_size,
                              hipStream_t stream) {
    const float* x  = (const float*)d_in[0];
    const int*   kc = (const int*)d_in[1];
    const float* w0 = (const float*)d_in[2];
    const float* w1 = (const float*)d_in[3];
    const float* w2 = (const float*)d_in[4];
    const float* w3 = (const float*)d_in[5];
    const float* w4 = (const float*)d_in[6];
    float* out = (float*)d_out;

    dim3 grid((B_ * K_) / 2, 8);  // (b*16 + k-pair, oh-quad) = 512 blocks, 512 threads
    logic_conv3d<<<grid, TPB, 0, stream>>>(x, kc, w0, w1, w2, w3, w4, out);
}

// Round 7
// 82.406 us; speedup vs baseline: 1.0551x; 1.0551x over previous
//
#include <hip/hip_runtime.h>

// LogicConv3d: B=4, C=3, H=W=D=32, K=32, S=16 leaves, tree depth 4 (31 LUT nodes).
// Out: (B, K, 30, 30, 30) = 3,456,000 fp32.
//
// R17 == R16 resubmit (R16 bench was an infra failure: "container failed
// twice", kernel never measured; source re-audited, no defect found).
//
// R16: half-width threads for VGPR slack + TLP. Evidence: R15 (all-LDS +
// depth-first + stagger) regressed +19% -> confirms split gathers; reverted.
// R13 core (25.3us) is invariant under pipe/staging/pipelining/occupancy-at-
// same-pressure => phase alternation (mem burst then VALU burst, time=SUM).
// R14 showed source rotation can't fix it: at the 128-VGPR cap (64 acc + 32
// operands) the scheduler has NO slack to keep prefetches live. Fix: v8f->v4f.
//  - per-thread state halves (v1[8]=32 VGPR + temps 16) -> 85-VGPR budget
//    via __launch_bounds__(512,6)
//  - 2 oh-rows/block -> slab 3c x 4h x 32 x 33 dw = 50,688B -> 3 blocks/CU
//    = 24 waves/CU (+50% TLP vs R13)
//  - finer mem ops: A-leaf 2x ds_read2_b32, B-leaf 1x dwordx4 (B wave-ops
//    perfectly dense: 64 lanes x 16B = exactly 8 cache lines)
// Kept from R13: k-pair per block (slab shared), A-leaves LDS / B-leaves
// global split, breadth-first fused levels 0+1, bases readfirstlane->SGPR.

#define B_  4
#define C_  3
#define H_  32
#define W_  32
#define D_  32
#define K_  32
#define S_  16
#define WS  33      // padded d-row stride (dwords); %32==1 rotates banks per ow
#define TPB 512

typedef float v4f __attribute__((ext_vector_type(4), aligned(4)));

__device__ __forceinline__ v4f lut4(v4f a, v4f b, float l0, float d1, float d2, float d3) {
    // E = l0 + a*d2 + b*d1 + (a*b)*d3 == fma(b, fma(a,d3,d1), fma(a,d2,l0))
    const v4f t0 = a * d2 + l0;
    const v4f t1 = a * d3 + d1;
    return b * t1 + t0;
}

__global__ __launch_bounds__(TPB, 6) void logic_conv3d(
    const float* __restrict__ x,
    const int*   __restrict__ kc,
    const float* __restrict__ w0,
    const float* __restrict__ w1,
    const float* __restrict__ w2,
    const float* __restrict__ w3,
    const float* __restrict__ w4,
    float*       __restrict__ out)
{
    __shared__ float4 s_lut[2][31];              // (l0, d1, d2, d3) per node, per kk
    __shared__ __align__(16) int s_lb[2][16];    // A-leaf base, slab coords, per kk
    __shared__ __align__(16) int s_gb[2][16];    // B-leaf base, global dword coords, per kk
    __shared__ __align__(16) float slab[12 * 32 * WS];  // 12672 dwords = 50688 B

    const int bx  = blockIdx.x;      // b*16 + kp
    const int b   = bx >> 4;
    const int k0  = (bx & 15) << 1;  // first k of this block's pair
    const int tid = threadIdx.x;
    const int oh0 = blockIdx.y * 2;  // first oh row of this block (0,2,...,28)

    // ---- per-block setup: 2 x (31 softmax->LUT delta form) + 2 x 32 leaf bases ----
    if (tid < 62) {
        const int kk   = (tid >= 31) ? 1 : 0;
        const int node = tid - kk * 31;
        const int k    = k0 + kk;
        const float* wp; int ln;
        if      (node < 16) { wp = w0; ln = node;      }
        else if (node < 24) { wp = w1; ln = node - 16; }
        else if (node < 28) { wp = w2; ln = node - 24; }
        else if (node < 30) { wp = w3; ln = node - 28; }
        else                { wp = w4; ln = 0;         }
        const float* wrow = wp + (ln * K_ + k) * 16;
        float lg[16];
        float m = -1e30f;
        #pragma unroll
        for (int g = 0; g < 16; ++g) { lg[g] = wrow[g]; m = fmaxf(m, lg[g]); }
        float z = 0.f;
        #pragma unroll
        for (int g = 0; g < 16; ++g) { lg[g] = __expf(lg[g] - m); z += lg[g]; }
        const float inv = 1.0f / z;
        float l0 = 0.f, l1 = 0.f, l2 = 0.f, l3 = 0.f;
        #pragma unroll
        for (int g = 0; g < 16; ++g) {
            float p = lg[g] * inv;           // GATES[g,t] = (g>>t)&1, t = 2*a+b
            if (g & 1) l0 += p;
            if (g & 2) l1 += p;
            if (g & 4) l2 += p;
            if (g & 8) l3 += p;
        }
        s_lut[kk][node] = make_float4(l0, l1 - l0, l2 - l0, (l3 - l2) - (l1 - l0));
    } else if (tid >= 64 && tid < 128) {
        const int idx  = tid - 64;           // kk*32 + tree*16 + s
        const int kk   = idx >> 5;
        const int tree = (idx >> 4) & 1;
        const int s    = idx & 15;
        const int k    = k0 + kk;
        const int off  = ((tree * K_ + k) * S_ + s) * 4;  // kc (2,K,S,4) = (h,w,d,c)
        const int h = kc[off + 0], w = kc[off + 1], d = kc[off + 2], c = kc[off + 3];
        if (tree == 0)
            s_lb[kk][s] = ((c * 4 + h) * 32 + w) * WS + d;    // slab coords (4 h-rows)
        else
            s_gb[kk][s] = ((c * H_ + h) * W_ + w) * D_ + d;   // global coords
    }

    // ---- stage slab: 12 planes (3c x 4h) of 32x32 dwords, coalesced float4 ----
    {
        const float* xb = x + (size_t)b * (C_ * H_ * W_ * D_);
        #pragma unroll
        for (int it = 0; it < 6; ++it) {
            const int idx   = it * TPB + tid;   // float4 index, 0..3071 (12*256)
            const int plane = idx >> 8;         // 0..11 = c*4 + dh
            const int f4    = idx & 255;
            const int c     = plane >> 2;
            const int dh    = plane & 3;
            const int h     = oh0 + dh;         // <= 28+3 = 31, no clamp needed
            const int w     = f4 >> 3;          // 0..31
            const int d4    = (f4 & 7) << 2;    // 0,4,...,28
            const float4 val = *(const float4*)(xb + ((c * H_ + h) * W_ + w) * D_ + d4);
            *(float4*)&slab[(plane * 32 + w) * WS + d4] = val;
        }
    }
    __syncthreads();

    // thread -> (oh_local 0..1, ow 0..31, quad of 4 consecutive od)
    const int ohl = tid >> 8;                // 0..1
    const int r   = tid & 255;
    const int ow  = r >> 3;                  // 0..31 (>=30 inactive)
    const int q   = r & 7;                   // 0..7
    const int od0 = (q < 7) ? (q << 2) : 26; // 0,4,...,24,26; q=7 overlaps q=6 by 2
    const int oh  = oh0 + ohl;               // <= 29 always

    if (ow < 30) {
        const int vo  = ohl * (32 * WS) + ow * WS + od0;            // slab offset (A)
        const int gvo = ohl * (W_ * D_) + ow * D_ + od0;            // global offset (B)
        const float* xg = x + (size_t)b * (C_ * H_ * W_ * D_) + oh0 * (W_ * D_);

        #pragma unroll
        for (int kk = 0; kk < 2; ++kk) {
            // ---- bases: aligned b128 reads + readfirstlane -> SGPRs ----
            int sA[16], sB[16];
            #pragma unroll
            for (int i = 0; i < 4; ++i) {
                const int4 qa = *(const int4*)&s_lb[kk][i * 4];
                sA[i * 4 + 0] = __builtin_amdgcn_readfirstlane(qa.x);
                sA[i * 4 + 1] = __builtin_amdgcn_readfirstlane(qa.y);
                sA[i * 4 + 2] = __builtin_amdgcn_readfirstlane(qa.z);
                sA[i * 4 + 3] = __builtin_amdgcn_readfirstlane(qa.w);
                const int4 qb = *(const int4*)&s_gb[kk][i * 4];
                sB[i * 4 + 0] = __builtin_amdgcn_readfirstlane(qb.x);
                sB[i * 4 + 1] = __builtin_amdgcn_readfirstlane(qb.y);
                sB[i * 4 + 2] = __builtin_amdgcn_readfirstlane(qb.z);
                sB[i * 4 + 3] = __builtin_amdgcn_readfirstlane(qb.w);
            }

            // ---- fused levels 0+1: leaf pair -> level-1 node ----
            v4f v1[8];
            #pragma unroll
            for (int j = 0; j < 8; ++j) {
                const int s0 = 2 * j, s1 = 2 * j + 1;
                const v4f A0 = *(const v4f*)&slab[sA[s0] + vo];
                const v4f B0 = *(const v4f*)(xg + sB[s0] + gvo);
                const float4 L0 = s_lut[kk][s0];
                const v4f t0 = lut4(A0, B0, L0.x, L0.y, L0.z, L0.w);
                const v4f A1 = *(const v4f*)&slab[sA[s1] + vo];
                const v4f B1 = *(const v4f*)(xg + sB[s1] + gvo);
                const float4 L1 = s_lut[kk][s1];
                const v4f t1 = lut4(A1, B1, L1.x, L1.y, L1.z, L1.w);
                const float4 LN = s_lut[kk][16 + j];
                v1[j] = lut4(t0, t1, LN.x, LN.y, LN.z, LN.w);
            }

            // ---- levels 2..4: widths 4,2,1 at node offsets 24,28,30 ----
            #pragma unroll
            for (int j = 0; j < 4; ++j) {
                const float4 L = s_lut[kk][24 + j];
                v1[j] = lut4(v1[2 * j], v1[2 * j + 1], L.x, L.y, L.z, L.w);
            }
            #pragma unroll
            for (int j = 0; j < 2; ++j) {
                const float4 L = s_lut[kk][28 + j];
                v1[j] = lut4(v1[2 * j], v1[2 * j + 1], L.x, L.y, L.z, L.w);
            }
            {
                const float4 L = s_lut[kk][30];
                v1[0] = lut4(v1[0], v1[1], L.x, L.y, L.z, L.w);
            }

            // store 4 consecutive od (q=7 overlaps q=6 with identical values)
            const int bk = b * K_ + k0 + kk;
            float* outp = out + (size_t)bk * 27000 + oh * 900 + ow * 30 + od0;
            *(v4f*)outp = v1[0];
        }
    }
}

extern "C" void kernel_launch(void* const* d_in, const int* in_sizes, int n_in,
                              void* d_out, int out_size, void* d_ws, size_t ws_size,
                              hipStream_t stream) {
    const float* x  = (const float*)d_in[0];
    const int*   kc = (const int*)d_in[1];
    const float* w0 = (const float*)d_in[2];
    const float* w1 = (const float*)d_in[3];
    const float* w2 = (const float*)d_in[4];
    const float* w3 = (const float*)d_in[5];
    const float* w4 = (const float*)d_in[6];
    float* out = (float*)d_out;

    dim3 grid((B_ * K_) / 2, 15);  // (b*16 + k-pair, oh-pair) = 960 blocks, 512 threads
    logic_conv3d<<<grid, TPB, 0, stream>>>(x, kc, w0, w1, w2, w3, w4, out);
}